// Round 1
// baseline (2001.707 us; speedup 1.0000x reference)
//
#include <hip/hip_runtime.h>
#include <cmath>

// Problem constants (B=1)
#define L_SEQ 2048
#define E_DIM 1024
#define NH    16
#define HD    64
// ws layout (floats): q[16][2048][64] | k | v | attn[2048][1024] | mrow[32768] | ilrow[32768]
// total = 4*2097152 + 2*32768 = 8,519,680 floats = 34.1 MB

// ---------------------------------------------------------------------------
// Generic tiled fp32 GEMM: C[m][n] = sum_k A[m][k] * W[n][k] + bias[n]
// mode 0: q  (xpos upscale, * D^-0.5, write [h][l][d])
// mode 1: k  (xpos downscale,        write [h][l][d])
// mode 2: v  (plain,                 write [h][l][d])
// mode 3: out-proj (plain,           write [l][e])
// ---------------------------------------------------------------------------
__global__ __launch_bounds__(256) void gemm_proj(
    const float* __restrict__ A, const float* __restrict__ W,
    const float* __restrict__ bias, float* __restrict__ outp, int mode)
{
  __shared__ float As[64][65];
  __shared__ float Ws[64][65];
  const int tid = threadIdx.x;
  const int tx = tid & 15, ty = tid >> 4;
  const int n0 = blockIdx.x * 64;
  const int m0 = blockIdx.y * 64;
  float acc[4][4] = {};
  for (int k0 = 0; k0 < E_DIM; k0 += 64) {
#pragma unroll
    for (int j = 0; j < 16; ++j) {
      int idx = j * 256 + tid;
      int mm = idx >> 6, kk = idx & 63;
      As[kk][mm] = A[(size_t)(m0 + mm) * E_DIM + k0 + kk];
      Ws[kk][mm] = W[(size_t)(n0 + mm) * E_DIM + k0 + kk];
    }
    __syncthreads();
#pragma unroll 16
    for (int kk = 0; kk < 64; ++kk) {
      float av[4], bv[4];
#pragma unroll
      for (int i = 0; i < 4; ++i) av[i] = As[kk][4 * ty + i];
#pragma unroll
      for (int j = 0; j < 4; ++j) bv[j] = Ws[kk][4 * tx + j];
#pragma unroll
      for (int i = 0; i < 4; ++i)
#pragma unroll
        for (int j = 0; j < 4; ++j) acc[i][j] += av[i] * bv[j];
    }
    __syncthreads();
  }

#pragma unroll
  for (int i = 0; i < 4; ++i) {
    int m = m0 + 4 * ty + i;  // sequence position l
    if (mode == 3) {
#pragma unroll
      for (int j = 0; j < 4; ++j) {
        int n = n0 + 4 * tx + j;
        outp[(size_t)m * E_DIM + n] = acc[i][j] + bias[n];
      }
    } else if (mode == 2) {
#pragma unroll
      for (int j = 0; j < 4; ++j) {
        int n = n0 + 4 * tx + j;
        int h = n >> 6, d = n & 63;
        outp[((size_t)h * L_SEQ + m) * HD + d] = acc[i][j] + bias[n];
      }
    } else {
      // xpos: pairs (2i, 2i+1); our 4 consecutive n are pair-aligned
#pragma unroll
      for (int j = 0; j < 4; j += 2) {
        int n = n0 + 4 * tx + j;
        int h = n >> 6, d = n & 63;   // d even
        int ii = d >> 1;
        float x0 = acc[i][j] + bias[n];
        float x1 = acc[i][j + 1] + bias[n + 1];
        float base = (2.0f * ii + 0.4f * HD) / (1.4f * HD);
        float sc = powf(base, (float)(m - L_SEQ / 2) * (1.0f / 512.0f));
        if (mode == 1) sc = 1.0f / sc;  // downscale for k
        float invf = powf(10000.0f, -(float)ii * (1.0f / 32.0f));
        float sn, cs;
        sincosf((float)m * invf, &sn, &cs);
        float y0 = (x0 * cs - x1 * sn) * sc;
        float y1 = (x1 * cs + x0 * sn) * sc;
        if (mode == 0) { y0 *= 0.125f; y1 *= 0.125f; }  // D^-0.5
        size_t o = ((size_t)h * L_SEQ + m) * HD + d;
        outp[o] = y0;
        outp[o + 1] = y1;
      }
    }
  }
}

// ---------------------------------------------------------------------------
// Raw scores: S[h][t][s] = q.k + mask[t][s] + rel[h][t][s], written to aw region
// ---------------------------------------------------------------------------
__global__ __launch_bounds__(256) void scores_kernel(
    const float* __restrict__ q, const float* __restrict__ k,
    const float* __restrict__ mask, const float* __restrict__ rel,
    float* __restrict__ Sout)
{
  __shared__ float qs[64][65];
  __shared__ float ks[64][65];
  const int tid = threadIdx.x;
  const int tx = tid & 15, ty = tid >> 4;
  const int h = blockIdx.z;
  const int t0 = blockIdx.y * 64, s0 = blockIdx.x * 64;
#pragma unroll
  for (int j = 0; j < 16; ++j) {
    int idx = j * 256 + tid;
    int r = idx >> 6, d = idx & 63;
    qs[d][r] = q[((size_t)h * L_SEQ + t0 + r) * HD + d];
    ks[d][r] = k[((size_t)h * L_SEQ + s0 + r) * HD + d];
  }
  __syncthreads();
  float acc[4][4] = {};
#pragma unroll 16
  for (int d = 0; d < 64; ++d) {
    float av[4], bv[4];
#pragma unroll
    for (int i = 0; i < 4; ++i) av[i] = qs[d][4 * ty + i];
#pragma unroll
    for (int j = 0; j < 4; ++j) bv[j] = ks[d][4 * tx + j];
#pragma unroll
    for (int i = 0; i < 4; ++i)
#pragma unroll
      for (int j = 0; j < 4; ++j) acc[i][j] += av[i] * bv[j];
  }
#pragma unroll
  for (int i = 0; i < 4; ++i) {
    int t = t0 + 4 * ty + i;
    size_t row = ((size_t)h * L_SEQ + t) * L_SEQ + s0 + 4 * tx;
    float4 mk = *(const float4*)(mask + (size_t)t * L_SEQ + s0 + 4 * tx);
    float4 rp = *(const float4*)(rel + row);
    float4 r4;
    r4.x = acc[i][0] + mk.x + rp.x;
    r4.y = acc[i][1] + mk.y + rp.y;
    r4.z = acc[i][2] + mk.z + rp.z;
    r4.w = acc[i][3] + mk.w + rp.w;
    *(float4*)(Sout + row) = r4;
  }
}

// ---------------------------------------------------------------------------
// Per-row max and 1/sum(exp) over raw scores
// ---------------------------------------------------------------------------
__global__ __launch_bounds__(256) void rowstats_kernel(
    const float* __restrict__ S, float* __restrict__ mrow, float* __restrict__ ilrow)
{
  __shared__ float red[256];
  const int tid = threadIdx.x;
  const int row = blockIdx.x;  // h*L + t
  const float* p = S + (size_t)row * L_SEQ;
  float mx = -3.0e38f;
  for (int i = tid; i < L_SEQ; i += 256) mx = fmaxf(mx, p[i]);
  red[tid] = mx;
  __syncthreads();
  for (int o = 128; o > 0; o >>= 1) {
    if (tid < o) red[tid] = fmaxf(red[tid], red[tid + o]);
    __syncthreads();
  }
  mx = red[0];
  __syncthreads();
  float sm = 0.f;
  for (int i = tid; i < L_SEQ; i += 256) sm += __expf(p[i] - mx);
  red[tid] = sm;
  __syncthreads();
  for (int o = 128; o > 0; o >>= 1) {
    if (tid < o) red[tid] += red[tid + o];
    __syncthreads();
  }
  if (tid == 0) {
    mrow[row] = mx;
    ilrow[row] = 1.0f / red[0];
  }
}

// ---------------------------------------------------------------------------
// Fused: normalize probs (write final aw) + PV GEMM -> attn[l][e] (pre-LN)
// S and aw alias the same memory (in-place overwrite, block owns its rows)
// ---------------------------------------------------------------------------
__global__ __launch_bounds__(256) void pv_kernel(
    const float* __restrict__ S, float* __restrict__ aw,
    const float* __restrict__ v,
    const float* __restrict__ mrow, const float* __restrict__ ilrow,
    float* __restrict__ attn)
{
  __shared__ float ps[64][65];
  __shared__ float vs[64][65];
  __shared__ float sm[64], sil[64];
  const int tid = threadIdx.x;
  const int tx = tid & 15, ty = tid >> 4;
  const int h = blockIdx.y;
  const int t0 = blockIdx.x * 64;
  if (tid < 64) {
    sm[tid] = mrow[h * L_SEQ + t0 + tid];
    sil[tid] = ilrow[h * L_SEQ + t0 + tid];
  }
  __syncthreads();
  float acc[4][4] = {};
  for (int s0 = 0; s0 < L_SEQ; s0 += 64) {
#pragma unroll
    for (int j = 0; j < 16; ++j) {
      int idx = j * 256 + tid;
      int tt = idx >> 6, ss = idx & 63;
      size_t off = ((size_t)(h * L_SEQ + t0 + tt)) * L_SEQ + s0 + ss;
      float pval = __expf(S[off] - sm[tt]) * sil[tt];
      ps[ss][tt] = pval;
      aw[off] = pval;
      vs[tt][ss] = v[((size_t)h * L_SEQ + s0 + tt) * HD + ss];  // vs[s][d]
    }
    __syncthreads();
#pragma unroll 16
    for (int ss = 0; ss < 64; ++ss) {
      float av[4], bv[4];
#pragma unroll
      for (int i = 0; i < 4; ++i) av[i] = ps[ss][4 * ty + i];
#pragma unroll
      for (int j = 0; j < 4; ++j) bv[j] = vs[ss][4 * tx + j];
#pragma unroll
      for (int i = 0; i < 4; ++i)
#pragma unroll
        for (int j = 0; j < 4; ++j) acc[i][j] += av[i] * bv[j];
    }
    __syncthreads();
  }
#pragma unroll
  for (int i = 0; i < 4; ++i) {
    int t = t0 + 4 * ty + i;
    float4 r4;
    r4.x = acc[i][0]; r4.y = acc[i][1]; r4.z = acc[i][2]; r4.w = acc[i][3];
    *(float4*)(attn + (size_t)t * E_DIM + h * HD + 4 * tx) = r4;
  }
}

// ---------------------------------------------------------------------------
// LayerNorm over E (in place)
// ---------------------------------------------------------------------------
__global__ __launch_bounds__(256) void ln_kernel(
    float* __restrict__ attn, const float* __restrict__ g, const float* __restrict__ b)
{
  __shared__ float r1[256], r2[256];
  const int tid = threadIdx.x;
  float* x = attn + (size_t)blockIdx.x * E_DIM;
  float s = 0.f, sq = 0.f;
  for (int i = tid; i < E_DIM; i += 256) {
    float vv = x[i];
    s += vv;
    sq += vv * vv;
  }
  r1[tid] = s; r2[tid] = sq;
  __syncthreads();
  for (int o = 128; o > 0; o >>= 1) {
    if (tid < o) { r1[tid] += r1[tid + o]; r2[tid] += r2[tid + o]; }
    __syncthreads();
  }
  float mu = r1[0] * (1.0f / E_DIM);
  float var = r2[0] * (1.0f / E_DIM) - mu * mu;
  float inv = rsqrtf(var + 1e-5f);
  for (int i = tid; i < E_DIM; i += 256) {
    x[i] = (x[i] - mu) * inv * g[i] + b[i];
  }
}

extern "C" void kernel_launch(void* const* d_in, const int* in_sizes, int n_in,
                              void* d_out, int out_size, void* d_ws, size_t ws_size,
                              hipStream_t stream) {
  const float* query = (const float*)d_in[0];
  const float* rel   = (const float*)d_in[1];
  const float* mask  = (const float*)d_in[2];
  const float* wq    = (const float*)d_in[3];
  const float* bq    = (const float*)d_in[4];
  const float* wk    = (const float*)d_in[5];
  const float* bk    = (const float*)d_in[6];
  const float* wv    = (const float*)d_in[7];
  const float* bv    = (const float*)d_in[8];
  const float* wo    = (const float*)d_in[9];
  const float* bo    = (const float*)d_in[10];
  const float* ln_g  = (const float*)d_in[11];
  const float* ln_b  = (const float*)d_in[12];

  float* out = (float*)d_out;                       // [2048][1024]
  float* aw  = out + (size_t)L_SEQ * E_DIM;         // [16][2048][2048]

  float* ws   = (float*)d_ws;
  float* qb   = ws;                                  // [16][2048][64]
  float* kb   = ws + 1 * 2097152;
  float* vb   = ws + 2 * 2097152;
  float* attn = ws + 3 * 2097152;                    // [2048][1024]
  float* mrow = ws + 4 * 2097152;                    // [32768]
  float* ilrw = mrow + 32768;                        // [32768]

  dim3 blk(256);
  gemm_proj<<<dim3(16, 32), blk, 0, stream>>>(query, wq, bq, qb, 0);
  gemm_proj<<<dim3(16, 32), blk, 0, stream>>>(query, wk, bk, kb, 1);
  gemm_proj<<<dim3(16, 32), blk, 0, stream>>>(query, wv, bv, vb, 2);
  scores_kernel<<<dim3(32, 32, 16), blk, 0, stream>>>(qb, kb, mask, rel, aw);
  rowstats_kernel<<<dim3(NH * L_SEQ), blk, 0, stream>>>(aw, mrow, ilrw);
  pv_kernel<<<dim3(32, 16), blk, 0, stream>>>(aw, aw, vb, mrow, ilrw, attn);
  ln_kernel<<<dim3(L_SEQ), blk, 0, stream>>>(attn, ln_g, ln_b);
  gemm_proj<<<dim3(16, 32), blk, 0, stream>>>(attn, wo, bo, out, 3);
}